// Round 20
// baseline (55.770 us; speedup 1.0000x reference)
//
#include <hip/hip_runtime.h>
#include <stdint.h>

// Problem constants
#define CHELEM 131072        // 2048*64 elements per chunk (flat-reshape chunk)

typedef __attribute__((ext_vector_type(4))) float   f32x4;
typedef __attribute__((ext_vector_type(8))) short   bh8;     // 8 bf16 in 4 VGPRs
typedef __attribute__((ext_vector_type(4))) unsigned short u16x4;
typedef __attribute__((ext_vector_type(8))) unsigned short u16x8;
typedef unsigned short u16;

__device__ inline u16 f2bf(float f) {
    union { float f; uint32_t u; } v; v.f = f;
    uint32_t u = v.u;
    u += 0x7FFF + ((u >> 16) & 1);         // RNE
    return (u16)(u >> 16);
}

// pack 2 f32 -> 2 bf16 in one u32 (RNE, matches f2bf)
__device__ inline uint32_t cvt2(float lo, float hi) {
    uint32_t r;
    asm("v_cvt_pk_bf16_f32 %0, %1, %2" : "=v"(r) : "v"(lo), "v"(hi));
    return r;
}

union U4B8 { uint4 u; bh8 b; };

// ---------------- K1: fused convert + QKV GEMM, BARRIER-FREE K-loop ----------------
// 64x128 tile, BK=64, 768 blocks. Wave w owns ALL 64 rows x cols [w*32,w*32+32).
// A (x): staged ONCE to LDS bf16 [64][512], XOR-swizzled 16B blocks
//   (byte ^= (row&7)<<4; write and read sides use the same involution -> free
//   2-way conflicts). ONE __syncthreads after the prologue.
// B (W): never in LDS. Each lane loads its exact MFMA B-frag source fp32
//   (2 float4 per (j,ks)), cvt_pk -> bh8 in regs, 1-step prefetch. K-loop has
//   NO barriers and NO inline-asm waits: all ordering intra-wave,
//   compiler-tracked. s-loop fully unrolled (static reg indexing, rule #20).
// Q (w==0): straight [4096][512]. K,V: TRANSPOSED per chunk Kt2[c][d][g][q]
// (c=m>>8, d=f&63, g=f>>6, q=m&255; row r=q*8+g bijection, same perm for K,V).
__global__ __launch_bounds__(256, 2) void k1_qkv(
        const float* __restrict__ x,
        const float* __restrict__ Wq, const float* __restrict__ Wk,
        const float* __restrict__ Wv,
        const float* __restrict__ bq, const float* __restrict__ bk,
        const float* __restrict__ bv,
        u16* __restrict__ Qb, u16* __restrict__ Kb, u16* __restrict__ Vb) {
    __shared__ u16 smem[32768];                 // A panel [64][512] bf16 (64KB); epi tile aliases
    const int tid  = threadIdx.x;
    const int lane = tid & 63;
    const int w    = tid >> 6;                  // wave owns cols [w*32, w*32+32)
    const int swz  = (blockIdx.x & 7) * 96 + (blockIdx.x >> 3);   // XCD swizzle
    const int mb = swz / 12, nb = swz % 12;
    const int wsel = nb >> 2;
    const int nloc = (nb & 3) * 128;
    const float4* x4 = (const float4*)x;        // [4096][128] float4
    const float4* W4 = (const float4*)((wsel == 0) ? Wq : ((wsel == 1) ? Wk : Wv));
    const float*  bias = (wsel == 0) ? bq : ((wsel == 1) ? bk : bv);
    u16*          out  = (wsel == 0) ? Qb : ((wsel == 1) ? Kb : Vb);
    const int m0 = mb * 64;

    // ---- B-frag loads: lane reads B[col=nloc+w*32+g*16+(lane&15)][8k fp32] ----
    const int browA = nloc + w * 32 + (lane & 15);        // + g*16
    const int bk4   = (lane >> 4) * 2;                    // float4 offset within 8-fp32 group
    auto issueB = [&](int s, float4* rb) {                // rb[8]: [(g*2+ks)*2+h]
#pragma unroll
        for (int g = 0; g < 2; ++g)
#pragma unroll
            for (int ks = 0; ks < 2; ++ks)
#pragma unroll
                for (int h = 0; h < 2; ++h)
                    rb[(g * 2 + ks) * 2 + h] =
                        W4[(size_t)(browA + g * 16) * 128 + s * 16 + ks * 8 + bk4 + h];
    };
    auto cvtB = [&](const float4* rb, bh8* bfr) {         // bfr[4]: [g*2+ks]
#pragma unroll
        for (int q = 0; q < 4; ++q) {
            U4B8 t;
            t.u.x = cvt2(rb[q * 2].x,     rb[q * 2].y);
            t.u.y = cvt2(rb[q * 2].z,     rb[q * 2].w);
            t.u.z = cvt2(rb[q * 2 + 1].x, rb[q * 2 + 1].y);
            t.u.w = cvt2(rb[q * 2 + 1].z, rb[q * 2 + 1].w);
            bfr[q] = t.b;
        }
    };

    // ---- A prologue: stage x panel [64][512] -> LDS bf16, swizzled ----
    float4 rb0[8], rb1[8];
    issueB(0, rb0);                             // covered by the whole prologue
    {
        float4 rx0[4], rx1[4];
        auto issueA = [&](int b, float4* rx) {
#pragma unroll
            for (int v = 0; v < 4; ++v) {
                const int idx = (b * 4 + v) * 256 + tid;  // [64 rows][128 c4]
                rx[v] = x4[(size_t)(m0 + (idx >> 7)) * 128 + (idx & 127)];
            }
        };
        auto writeA = [&](int b, const float4* rx) {
#pragma unroll
            for (int v = 0; v < 4; ++v) {
                const int idx = (b * 4 + v) * 256 + tid;
                const int row = idx >> 7, c4 = idx & 127;
                uint2 pk; pk.x = cvt2(rx[v].x, rx[v].y); pk.y = cvt2(rx[v].z, rx[v].w);
                *(uint2*)((char*)smem + row * 1024 + ((c4 * 8) ^ ((row & 7) << 4))) = pk;
            }
        };
        issueA(0, rx0);
#pragma unroll
        for (int b = 0; b < 8; ++b) {
            if (b & 1) { if (b < 7) issueA(b + 1, rx0); writeA(b, rx1); }
            else       { if (b < 7) issueA(b + 1, rx1); writeA(b, rx0); }
        }
    }
    __syncthreads();                            // the ONLY main-path barrier

    // ---- barrier-free K-loop (fully unrolled; 1-deep B prefetch) ----
    f32x4 acc[4][2] = {};
    const int arow_l = lane & 15;
    const int akoff  = (lane >> 4) * 8;
#pragma unroll
    for (int s = 0; s < 8; ++s) {
        bh8 bfr[4];
        if (s & 1) { if (s < 7) issueB(s + 1, rb0); cvtB(rb1, bfr); }
        else       { if (s < 7) issueB(s + 1, rb1); cvtB(rb0, bfr); }
#pragma unroll
        for (int ks = 0; ks < 2; ++ks) {
            bh8 aa[4];
#pragma unroll
            for (int i = 0; i < 4; ++i) {
                const int row = i * 16 + arow_l;
                const int kk2 = ((s * 64 + ks * 32 + akoff) * 2) ^ ((row & 7) << 4);
                aa[i] = *(const bh8*)((const char*)smem + row * 1024 + kk2);
            }
#pragma unroll
            for (int i = 0; i < 4; ++i)
#pragma unroll
                for (int j = 0; j < 2; ++j)
                    acc[i][j] = __builtin_amdgcn_mfma_f32_16x16x32_bf16(
                        aa[i], bfr[j * 2 + ks], acc[i][j], 0, 0, 0);
        }
    }

    if (wsel == 0) {
        // straight store (Q): rows i*16.., cols nloc + w*32 + j*16 + (lane&15)
#pragma unroll
        for (int i = 0; i < 4; ++i) {
            const int row_base = m0 + i * 16 + ((lane >> 4) * 4);
#pragma unroll
            for (int j = 0; j < 2; ++j) {
                const int col = nloc + w * 32 + j * 16 + (lane & 15);
                const float bv_ = bias[col];
#pragma unroll
                for (int r = 0; r < 4; ++r)
                    out[(size_t)(row_base + r) * 512 + col] = f2bf(acc[i][j][r] + bv_);
            }
        }
    } else {
        // transposed store (K,V): all waves done reading A -> reuse smem as tile
        __syncthreads();
        u16 (*tile)[130] = (u16(*)[130])smem;
#pragma unroll
        for (int i = 0; i < 4; ++i) {
            const int ml = i * 16 + ((lane >> 4) * 4);
#pragma unroll
            for (int j = 0; j < 2; ++j) {
                const int nl = w * 32 + j * 16 + (lane & 15);
                const float bv_ = bias[nloc + nl];
#pragma unroll
                for (int r = 0; r < 4; ++r)
                    tile[ml + r][nl] = f2bf(acc[i][j][r] + bv_);
            }
        }
        __syncthreads();
        const int ncol  = tid & 127;
        const int mhalf = tid >> 7;
        const int g = (nb & 3) * 2 + (ncol >> 6);
        const int d = ncol & 63;
        const int c = mb >> 2;
        const int qbase = (mb & 3) * 64 + mhalf * 32;
        u16* dst = out + (size_t)c * CHELEM + d * 2048 + g * 256 + qbase;
#pragma unroll
        for (int v = 0; v < 4; ++v) {
            u16x8 t;
#pragma unroll
            for (int j = 0; j < 8; ++j)
                t[j] = tile[mhalf * 32 + v * 8 + j][ncol];
            *(u16x8*)(dst + v * 8) = t;
        }
    }
}

// ---------------- K2: Pb[c][d][e] = scale * sum_k Vt2[c][d][k] * Kt2[c][e][k] ----------------
// (verbatim R8/R14 winner) 256 blocks: c = bid%16, sub = bid/16 -> 16x16 (d,e)
// subtile. 4 waves split K=2048; frags direct from global; LDS reduce.
__global__ __launch_bounds__(256) void k2_pmat(
        const u16* __restrict__ Kt2, const u16* __restrict__ Vt2,
        u16* __restrict__ Pb) {
    __shared__ float red[4][16][16];
    const int tid = threadIdx.x;
    const int lane = tid & 63, w = tid >> 6;
    const int c   = blockIdx.x & 15;
    const int sub = blockIdx.x >> 4;
    const int dq = sub >> 2, eq = sub & 3;
    const u16* Vc = Vt2 + (size_t)c * CHELEM;
    const u16* Kc = Kt2 + (size_t)c * CHELEM;
    const int krow = lane & 15;
    const int arow = (dq * 16 + krow) * 2048;
    const int brow = (eq * 16 + krow) * 2048;
    const int kb = w * 512 + (lane >> 4) * 8;

    f32x4 acc = {};
#pragma unroll
    for (int kt = 0; kt < 16; ++kt) {
        const int k0 = kb + kt * 32;
        bh8 a = *(const bh8*)&Vc[arow + k0];
        bh8 b = *(const bh8*)&Kc[brow + k0];
        acc = __builtin_amdgcn_mfma_f32_16x16x32_bf16(a, b, acc, 0, 0, 0);
    }
#pragma unroll
    for (int r = 0; r < 4; ++r)
        red[w][(lane >> 4) * 4 + r][lane & 15] = acc[r];
    __syncthreads();
    const int row = tid >> 4, col = tid & 15;
    float s = red[0][row][col] + red[1][row][col] + red[2][row][col] + red[3][row][col];
    Pb[c * 4096 + (dq * 16 + row) * 64 + eq * 16 + col] = f2bf(s * 0.125f);  // scale = DIM^-0.5
}

// ---------------- K3: out_c = Q_c @ P_c^T  (verbatim R14: 256 blocks, 16 rows x 512 cols) ----------------
__global__ __launch_bounds__(256) void k3_out(
        const u16* __restrict__ Qb, const u16* __restrict__ Pb,
        float* __restrict__ outp) {
    const int tid = threadIdx.x;
    const int lane = tid & 63, w = tid >> 6;
    const int bid = blockIdx.x;
    const int bb = bid >> 7;                 // batch
    const int ib = bid & 127;                // 128 row-blocks of 16 per batch
    const int i0 = ib * 16;
    const int dbase = w * 16;                // wave owns one 16-wide d-group
    const int krow = lane & 15;
    const int koff = (lane >> 4) * 8;

    f32x4 acc[8] = {};                       // [head]
#pragma unroll
    for (int h = 0; h < 8; ++h) {
        const int c = h * 2 + bb;
        const u16* Qc = Qb + (size_t)c * CHELEM;
        const u16* Pc = Pb + c * 4096;
#pragma unroll
        for (int ks = 0; ks < 2; ++ks) {
            bh8 a = *(const bh8*)&Qc[(i0 + krow) * 64 + ks * 32 + koff];
            bh8 b = *(const bh8*)&Pc[(dbase + krow) * 64 + ks * 32 + koff];
            acc[h] = __builtin_amdgcn_mfma_f32_16x16x32_bf16(a, b, acc[h], 0, 0, 0);
        }
    }
    const int orow_base = bb * 2048 + i0 + (lane >> 4) * 4;
    const int d = dbase + (lane & 15);
#pragma unroll
    for (int r = 0; r < 4; ++r) {
        f32x4 lo = {acc[0][r], acc[1][r], acc[2][r], acc[3][r]};
        f32x4 hi = {acc[4][r], acc[5][r], acc[6][r], acc[7][r]};
        float* dst = outp + (size_t)(orow_base + r) * 512 + d * 8;
        *(f32x4*)dst = lo;
        *(f32x4*)(dst + 4) = hi;
    }
}

extern "C" void kernel_launch(void* const* d_in, const int* in_sizes, int n_in,
                              void* d_out, int out_size, void* d_ws, size_t ws_size,
                              hipStream_t stream) {
    const float* x  = (const float*)d_in[0];
    const float* Wq = (const float*)d_in[1];
    const float* bq = (const float*)d_in[2];
    const float* Wk = (const float*)d_in[3];
    const float* bk = (const float*)d_in[4];
    const float* Wv = (const float*)d_in[5];
    const float* bv = (const float*)d_in[6];
    float* outp = (float*)d_out;

    u16* Qb = (u16*)d_ws;                 // 4096*512 (straight)
    u16* Kb = Qb + 2097152;               // Kt2 transposed chunks
    u16* Vb = Kb + 2097152;               // Vt2 transposed chunks
    u16* Pb = Vb + 2097152;               // 16*64*64

    k1_qkv<<<768, 256, 0, stream>>>(x, Wq, Wk, Wv, bq, bk, bv, Qb, Kb, Vb);
    k2_pmat<<<256, 256, 0, stream>>>(Kb, Vb, Pb);
    k3_out<<<256, 256, 0, stream>>>(Qb, Pb, outp);
}

// Round 21
// 35.873 us; speedup vs baseline: 1.5547x; 1.5547x over previous
//
#include <hip/hip_runtime.h>
#include <stdint.h>

// Problem constants
#define CHELEM 131072        // 2048*64 elements per chunk (flat-reshape chunk)

typedef __attribute__((ext_vector_type(4))) float   f32x4;
typedef __attribute__((ext_vector_type(8))) short   bh8;     // 8 bf16 in 4 VGPRs
typedef __attribute__((ext_vector_type(4))) unsigned short u16x4;
typedef __attribute__((ext_vector_type(8))) unsigned short u16x8;
typedef unsigned short u16;

__device__ inline u16 f2bf(float f) {
    union { float f; uint32_t u; } v; v.f = f;
    uint32_t u = v.u;
    u += 0x7FFF + ((u >> 16) & 1);         // RNE
    return (u16)(u >> 16);
}

// pack 2 f32 -> 2 bf16 in one u32 (RNE, matches f2bf)
__device__ inline uint32_t cvt2(float lo, float hi) {
    uint32_t r;
    asm("v_cvt_pk_bf16_f32 %0, %1, %2" : "=v"(r) : "v"(lo), "v"(hi));
    return r;
}

// ---------------- K1: fused convert + QKV projection GEMM (verbatim R19 winner) ----------------
// 64x128 tile, BK=64, 768 blocks = 3/CU, dbuf, fused fp32->bf16 staging,
// interleaved body: issue -> compute(ks0) -> cvt_write_A -> compute(ks1) ->
// cvt_write_B -> sync. Sync skeleton is __syncthreads-only (race-free).
// Q (w==0): straight [4096][512]. K,V: TRANSPOSED per chunk Kt2[c][d][g][q]
// (c=m>>8, d=f&63, g=f>>6, q=m&255; row r=q*8+g bijection, same perm for K,V).
__global__ __launch_bounds__(256, 3) void k1_qkv(
        const float* __restrict__ x,
        const float* __restrict__ Wq, const float* __restrict__ Wk,
        const float* __restrict__ Wv,
        const float* __restrict__ bq, const float* __restrict__ bk,
        const float* __restrict__ bv,
        u16* __restrict__ Qb, u16* __restrict__ Kb, u16* __restrict__ Vb) {
    __shared__ u16 smem[2][12288];              // per buf: lA[64][64] + lB[128][64] bf16
    const int tid  = threadIdx.x;
    const int lane = tid & 63, wid = tid >> 6;
    const int wr = wid >> 1, wc = wid & 1;
    const int swz  = (blockIdx.x & 7) * 96 + (blockIdx.x >> 3);   // XCD swizzle
    const int mb = swz / 12, nb = swz % 12;
    const int w    = nb >> 2;
    const int nloc = (nb & 3) * 128;
    const float4* x4 = (const float4*)x;        // [4096][128] float4
    const float4* W4 = (const float4*)((w == 0) ? Wq : ((w == 1) ? Wk : Wv));
    const float*  bias = (w == 0) ? bq : ((w == 1) ? bk : bv);
    u16*          out  = (w == 0) ? Qb : ((w == 1) ? Kb : Vb);
    const int m0 = mb * 64;

    f32x4 acc[2][4] = {};
    float4 ra[4], rb[8];                        // in-flight fp32 staging regs

    auto issue = [&](int kb) {
        const int k4 = kb * 16;
#pragma unroll
        for (int v = 0; v < 4; ++v) {           // A: 64 rows x 16 float4
            const int idx = v * 256 + tid;
            ra[v] = x4[(size_t)(m0 + (idx >> 4)) * 128 + k4 + (idx & 15)];
        }
#pragma unroll
        for (int v = 0; v < 8; ++v) {           // B: 128 rows x 16 float4
            const int idx = v * 256 + tid;
            rb[v] = W4[(size_t)(nloc + (idx >> 4)) * 128 + k4 + (idx & 15)];
        }
    };
    auto cvt_write_A = [&](int b) {             // waits only ra (issued first)
        u16* bA = smem[b];
#pragma unroll
        for (int v = 0; v < 4; ++v) {
            const int idx = v * 256 + tid;
            uint2 pk; pk.x = cvt2(ra[v].x, ra[v].y); pk.y = cvt2(ra[v].z, ra[v].w);
            *(uint2*)&bA[(idx >> 4) * 64 + (idx & 15) * 4] = pk;
        }
    };
    auto cvt_write_B = [&](int b) {             // waits rb (a full MFMA phase later)
        u16* bB = smem[b] + 4096;
#pragma unroll
        for (int v = 0; v < 8; ++v) {
            const int idx = v * 256 + tid;
            uint2 pk; pk.x = cvt2(rb[v].x, rb[v].y); pk.y = cvt2(rb[v].z, rb[v].w);
            *(uint2*)&bB[(idx >> 4) * 64 + (idx & 15) * 4] = pk;
        }
    };
    auto compute_ks = [&](int b, int ks) {
        const u16* bA = smem[b];
        const u16* bB = smem[b] + 4096;
        const int kk = ks * 32 + (lane >> 4) * 8;
        bh8 a[2], bfr[4];
#pragma unroll
        for (int i = 0; i < 2; ++i)
            a[i] = *(const bh8*)&bA[(wr * 32 + i * 16 + (lane & 15)) * 64 + kk];
#pragma unroll
        for (int j = 0; j < 4; ++j)
            bfr[j] = *(const bh8*)&bB[(wc * 64 + j * 16 + (lane & 15)) * 64 + kk];
#pragma unroll
        for (int i = 0; i < 2; ++i)
#pragma unroll
            for (int j = 0; j < 4; ++j)
                acc[i][j] = __builtin_amdgcn_mfma_f32_16x16x32_bf16(a[i], bfr[j], acc[i][j], 0, 0, 0);
    };

    issue(0);
    cvt_write_A(0);
    cvt_write_B(0);
    __syncthreads();                            // buf0 ready
    for (int kb = 0; kb < 8; ++kb) {
        const int cur = kb & 1, nxt = (kb + 1) & 1;
        if (kb < 7) issue(kb + 1);              // 12 loads fly
        compute_ks(cur, 0);                     // MFMA under loads
        if (kb < 7) cvt_write_A(nxt);           // ra landed; write other buf
        compute_ks(cur, 1);                     // more cover for rb
        if (kb < 7) cvt_write_B(nxt);
        __syncthreads();                        // next buf ready / cur buf free
    }

    if (w == 0) {
        // straight store (Q)
#pragma unroll
        for (int i = 0; i < 2; ++i) {
            const int row_base = m0 + wr * 32 + i * 16 + ((lane >> 4) * 4);
#pragma unroll
            for (int j = 0; j < 4; ++j) {
                const int col = nloc + wc * 64 + j * 16 + (lane & 15);
                const float bv_ = bias[col];
#pragma unroll
                for (int r = 0; r < 4; ++r)
                    out[(size_t)(row_base + r) * 512 + col] = f2bf(acc[i][j][r] + bv_);
            }
        }
    } else {
        // transposed store (K,V): stage to padded LDS tile (aliases smem),
        // scatter to Kt2[c][d][g][q]. Loop's final __syncthreads precedes.
        u16 (*tile)[130] = (u16(*)[130])smem;
#pragma unroll
        for (int i = 0; i < 2; ++i) {
            const int ml = wr * 32 + i * 16 + ((lane >> 4) * 4);
#pragma unroll
            for (int j = 0; j < 4; ++j) {
                const int nl = wc * 64 + j * 16 + (lane & 15);
                const float bv_ = bias[nloc + nl];
#pragma unroll
                for (int r = 0; r < 4; ++r)
                    tile[ml + r][nl] = f2bf(acc[i][j][r] + bv_);
            }
        }
        __syncthreads();
        const int ncol  = tid & 127;
        const int mhalf = tid >> 7;
        const int g = (nb & 3) * 2 + (ncol >> 6);
        const int d = ncol & 63;
        const int c = mb >> 2;
        const int qbase = (mb & 3) * 64 + mhalf * 32;
        u16* dst = out + (size_t)c * CHELEM + d * 2048 + g * 256 + qbase;
#pragma unroll
        for (int v = 0; v < 4; ++v) {
            u16x8 t;
#pragma unroll
            for (int j = 0; j < 8; ++j)
                t[j] = tile[mhalf * 32 + v * 8 + j][ncol];
            *(u16x8*)(dst + v * 8) = t;
        }
    }
}

// ---------------- K2: Pb[c][d][e] = scale * sum_k Vt2[c][d][k] * Kt2[c][e][k] ----------------
// (verbatim R8/R14 winner) 256 blocks: c = bid%16, sub = bid/16 -> 16x16 (d,e)
// subtile. 4 waves split K=2048; frags direct from global; LDS reduce.
__global__ __launch_bounds__(256) void k2_pmat(
        const u16* __restrict__ Kt2, const u16* __restrict__ Vt2,
        u16* __restrict__ Pb) {
    __shared__ float red[4][16][16];
    const int tid = threadIdx.x;
    const int lane = tid & 63, w = tid >> 6;
    const int c   = blockIdx.x & 15;
    const int sub = blockIdx.x >> 4;
    const int dq = sub >> 2, eq = sub & 3;
    const u16* Vc = Vt2 + (size_t)c * CHELEM;
    const u16* Kc = Kt2 + (size_t)c * CHELEM;
    const int krow = lane & 15;
    const int arow = (dq * 16 + krow) * 2048;
    const int brow = (eq * 16 + krow) * 2048;
    const int kb = w * 512 + (lane >> 4) * 8;

    f32x4 acc = {};
#pragma unroll
    for (int kt = 0; kt < 16; ++kt) {
        const int k0 = kb + kt * 32;
        bh8 a = *(const bh8*)&Vc[arow + k0];
        bh8 b = *(const bh8*)&Kc[brow + k0];
        acc = __builtin_amdgcn_mfma_f32_16x16x32_bf16(a, b, acc, 0, 0, 0);
    }
#pragma unroll
    for (int r = 0; r < 4; ++r)
        red[w][(lane >> 4) * 4 + r][lane & 15] = acc[r];
    __syncthreads();
    const int row = tid >> 4, col = tid & 15;
    float s = red[0][row][col] + red[1][row][col] + red[2][row][col] + red[3][row][col];
    Pb[c * 4096 + (dq * 16 + row) * 64 + eq * 16 + col] = f2bf(s * 0.125f);  // scale = DIM^-0.5
}

// ---------------- K3: out_c = Q_c @ P_c^T  (verbatim R14: 256 blocks, 16 rows x 512 cols) ----------------
__global__ __launch_bounds__(256) void k3_out(
        const u16* __restrict__ Qb, const u16* __restrict__ Pb,
        float* __restrict__ outp) {
    const int tid = threadIdx.x;
    const int lane = tid & 63, w = tid >> 6;
    const int bid = blockIdx.x;
    const int bb = bid >> 7;                 // batch
    const int ib = bid & 127;                // 128 row-blocks of 16 per batch
    const int i0 = ib * 16;
    const int dbase = w * 16;                // wave owns one 16-wide d-group
    const int krow = lane & 15;
    const int koff = (lane >> 4) * 8;

    f32x4 acc[8] = {};                       // [head]
#pragma unroll
    for (int h = 0; h < 8; ++h) {
        const int c = h * 2 + bb;
        const u16* Qc = Qb + (size_t)c * CHELEM;
        const u16* Pc = Pb + c * 4096;
#pragma unroll
        for (int ks = 0; ks < 2; ++ks) {
            bh8 a = *(const bh8*)&Qc[(i0 + krow) * 64 + ks * 32 + koff];
            bh8 b = *(const bh8*)&Pc[(dbase + krow) * 64 + ks * 32 + koff];
            acc[h] = __builtin_amdgcn_mfma_f32_16x16x32_bf16(a, b, acc[h], 0, 0, 0);
        }
    }
    const int orow_base = bb * 2048 + i0 + (lane >> 4) * 4;
    const int d = dbase + (lane & 15);
#pragma unroll
    for (int r = 0; r < 4; ++r) {
        f32x4 lo = {acc[0][r], acc[1][r], acc[2][r], acc[3][r]};
        f32x4 hi = {acc[4][r], acc[5][r], acc[6][r], acc[7][r]};
        float* dst = outp + (size_t)(orow_base + r) * 512 + d * 8;
        *(f32x4*)dst = lo;
        *(f32x4*)(dst + 4) = hi;
    }
}

extern "C" void kernel_launch(void* const* d_in, const int* in_sizes, int n_in,
                              void* d_out, int out_size, void* d_ws, size_t ws_size,
                              hipStream_t stream) {
    const float* x  = (const float*)d_in[0];
    const float* Wq = (const float*)d_in[1];
    const float* bq = (const float*)d_in[2];
    const float* Wk = (const float*)d_in[3];
    const float* bk = (const float*)d_in[4];
    const float* Wv = (const float*)d_in[5];
    const float* bv = (const float*)d_in[6];
    float* outp = (float*)d_out;

    u16* Qb = (u16*)d_ws;                 // 4096*512 (straight)
    u16* Kb = Qb + 2097152;               // Kt2 transposed chunks
    u16* Vb = Kb + 2097152;               // Vt2 transposed chunks
    u16* Pb = Vb + 2097152;               // 16*64*64

    k1_qkv<<<768, 256, 0, stream>>>(x, Wq, Wk, Wv, bq, bk, bv, Qb, Kb, Vb);
    k2_pmat<<<256, 256, 0, stream>>>(Kb, Vb, Pb);
    k3_out<<<256, 256, 0, stream>>>(Qb, Pb, outp);
}